// Round 5
// baseline (410.849 us; speedup 1.0000x reference)
//
#include <hip/hip_runtime.h>

// Problem constants (from reference setup_inputs / NUM_DISPARITIES)
constexpr int B = 2, C = 32, H = 136, W = 240, D = 48;
constexpr int PLANE  = H * W;          // 32640 floats per (b,c,d) plane
constexpr int SLABR  = 8;              // rows per block slab
constexpr int NSLAB  = H / SLABR;      // 17 slabs
constexpr int NBLK   = B * C * NSLAB;  // 1088 blocks
constexpr int SLAB4  = SLABR * W / 4;  // 480 float4 per (d, slab)
constexpr int LROW4  = 76;             // float4 per LDS row: 16 pad + 60 data
constexpr float CLAMPV = 1000.0f;

typedef float v4f __attribute__((ext_vector_type(4)));

__device__ __forceinline__ float clampv(float x) {
    return fminf(CLAMPV, fmaxf(-CLAMPV, x));
}
// exact floor(s/60) for s in [0, 480)  (2185 = ceil(2^17/60); error bound checked)
__device__ __forceinline__ int div60(int s) { return (s * 2185) >> 17; }

// Theory under test: rounds 0-4 all stored with 60-lane masks / 960B row chunks
// whose edges only partially cover 128B L2 lines -> suspected read-for-ownership
// doubles HBM traffic (401MB RFO read + 401MB write = 5.5 TB/s at 146us ~= the
// achievable ceiling). This kernel makes EVERY store a full-wave (or exact
// half-wave) 128B-aligned fully-line-covering write, exactly like the 6.4 TB/s
// fillBufferAligned: slab of 8 rows = 7680B per d = 7x1024B full-wave chunks +
// 1x512B half-wave chunk, all 128B-aligned (plane stride 130560 = 1020*128,
// slab stride 7680 = 60*128).
//
// Wave g owns disparities d = 12g + 4q + j (q<3, j<4 compile-time). Output is
// addressed FLAT within the slab: lane handles float4 slot s = 64c + lane,
// row r = s/60 (exact magic div), col4 = s - 60r. LDS sliding-window gather:
// window start t = 304r + 64 + (4*col4 - d) floats; 16B-aligned X/Y pair
//   slotQ = 16r + s + 16 - (3g + q),  P = slotQ-1
//   j=0: [Q0 Q1 Q2 Q3]  j=1: [P3 Q0 Q1 Q2]  j=2: [P2 P3 Q0 Q1]  j=3: [P1 P2 P3 Q0]
// (row-crossing adds +64 floats = bank/alignment neutral). The 64-float zero
// pad per LDS row implements the w<d mask for free. Left float4s live in
// registers, reused across all 12 of the wave's disparities.
__global__ __launch_bounds__(256) void CostVolume_4939212390829_kernel(
        const float* __restrict__ left,
        const float* __restrict__ right,
        float* __restrict__ out) {
    const int blk  = blockIdx.x;
    const int bc   = blk / NSLAB;
    const int h0   = (blk - bc * NSLAB) * SLABR;
    const int tid  = threadIdx.x;
    const int g    = tid >> 6;       // wave 0..3 -> d in [12g, 12g+12)
    const int lane = tid & 63;

    __shared__ v4f sR[SLABR * LROW4];    // 9728 B

    const v4f* __restrict__ rbase4 =
        (const v4f*)(right + (size_t)bc * PLANE + (size_t)h0 * W);
    const v4f* __restrict__ lbase4 =
        (const v4f*)(left  + (size_t)bc * PLANE + (size_t)h0 * W);

    // zero pads: 8 rows x 16 float4
    if (tid < 128) sR[(tid >> 4) * LROW4 + (tid & 15)] = (v4f){0.f,0.f,0.f,0.f};
    // stage right slab: data slot i -> LDS slot i + 16*row + 16
    for (int i = tid; i < SLAB4; i += 256) {
        const int r = div60(i);
        sR[i + 16 * r + 16] = rbase4[i];
    }
    __syncthreads();

    // per-thread precompute for the 8 flat chunks (c=7 is the half-chunk)
    v4f      l4[8];
    int      q0slot[8];
    uint32_t ob[8];
    const uint32_t oBase0 = (uint32_t)(bc * D + 12 * g) * PLANE + (uint32_t)h0 * W;
    #pragma unroll
    for (int c = 0; c < 8; ++c) {
        int s  = 64 * c + lane;
        int ss = (s < SLAB4) ? s : (SLAB4 - 1);   // clamp; tail lanes' stores are predicated off
        const int r = div60(ss);
        l4[c]      = lbase4[ss];
        q0slot[c]  = ss + 16 * r + 16 - 3 * g;
        ob[c]      = oBase0 + 4u * (uint32_t)ss;
    }

    #pragma unroll
    for (int c = 0; c < 8; ++c) {
        const bool act = (c < 7) || (lane < 32);
        #pragma unroll
        for (int q = 0; q < 3; ++q) {
            const int slot = q0slot[c] - q;
            const v4f Q = sR[slot];
            const v4f P = sR[slot - 1];
            if (act) {
                float* __restrict__ o0 = out + ob[c] + (uint32_t)(4 * q) * PLANE;
                v4f v;
                // j=0 : d = 12g+4q
                v.x = clampv(l4[c].x * Q.x); v.y = clampv(l4[c].y * Q.y);
                v.z = clampv(l4[c].z * Q.z); v.w = clampv(l4[c].w * Q.w);
                *(v4f*)(o0) = v;
                // j=1
                v.x = clampv(l4[c].x * P.w); v.y = clampv(l4[c].y * Q.x);
                v.z = clampv(l4[c].z * Q.y); v.w = clampv(l4[c].w * Q.z);
                *(v4f*)(o0 + PLANE) = v;
                // j=2
                v.x = clampv(l4[c].x * P.z); v.y = clampv(l4[c].y * P.w);
                v.z = clampv(l4[c].z * Q.x); v.w = clampv(l4[c].w * Q.y);
                *(v4f*)(o0 + 2 * PLANE) = v;
                // j=3
                v.x = clampv(l4[c].x * P.y); v.y = clampv(l4[c].y * P.z);
                v.z = clampv(l4[c].z * P.w); v.w = clampv(l4[c].w * Q.x);
                *(v4f*)(o0 + 3 * PLANE) = v;
            }
        }
    }
}

extern "C" void kernel_launch(void* const* d_in, const int* in_sizes, int n_in,
                              void* d_out, int out_size, void* d_ws, size_t ws_size,
                              hipStream_t stream) {
    const float* left  = (const float*)d_in[0];
    const float* right = (const float*)d_in[1];
    float* out = (float*)d_out;
    (void)in_sizes; (void)n_in; (void)out_size; (void)d_ws; (void)ws_size;

    CostVolume_4939212390829_kernel<<<NBLK, 256, 0, stream>>>(left, right, out);
}